// Round 15
// baseline (128.561 us; speedup 1.0000x reference)
//
#include <hip/hip_runtime.h>

#define BATCH 4
#define NPIX (512*512)
#define NOBJ 8
#define NPART 16
#define NINST 24
#define KB 128
#define L2E 1.44269504f
#define INV511 (1.0f/511.0f)

__device__ __forceinline__ float fexp2(float x){ return __builtin_amdgcn_exp2f(x); }
__device__ __forceinline__ float frcp(float x){ return __builtin_amdgcn_rcpf(x); }
__device__ __forceinline__ float ftanh(float x){ return 1.f - 2.f*frcp(fexp2(2.f*L2E*x) + 1.f); }
__device__ __forceinline__ float fsig(float x){ return frcp(1.f + fexp2(-L2E*x)); }

// ws: [0, B*24*Cn*KB) u32 partial hists packed (cnt | fg<<16), layout [img][inst][Cn][KB]
//     then accum f32 [B][24][5] (cnt, sx, sy, ssig, ssig2)   (zeroed via hipMemsetAsync)

// grid (NPIX/4096, BATCH), 256 thr, 16 px/thread vec4 (run-combined LDS atomics).
__global__ __launch_bounds__(256) void k_reduce(
    const float* __restrict__ pred, const int* __restrict__ obj_inst,
    const int* __restrict__ parts_inst, float* __restrict__ accum){
  __shared__ float acc[NINST*5];
  const int tid = threadIdx.x;
  if (tid < NINST*5) acc[tid] = 0.f;
  __syncthreads();
  const int img = blockIdx.y;
  const float* predb = pred + (size_t)img*8*NPIX;
  const int pix0 = blockIdx.x*4096 + tid*16;
  const int v = pix0 >> 2;
  const int*   obase = obj_inst   + (size_t)img*NPIX;
  const int*   pbase = parts_inst + (size_t)img*NPIX;
  int   oid[16], pid[16];
  float so[16], sp[16];
  #pragma unroll
  for (int q=0;q<4;++q){
    const int4 a = ((const int4*)obase)[v+q];
    oid[4*q]=a.x; oid[4*q+1]=a.y; oid[4*q+2]=a.z; oid[4*q+3]=a.w;
  }
  #pragma unroll
  for (int q=0;q<4;++q){
    const int4 a = ((const int4*)pbase)[v+q];
    pid[4*q]=a.x; pid[4*q+1]=a.y; pid[4*q+2]=a.z; pid[4*q+3]=a.w;
  }
  #pragma unroll
  for (int q=0;q<4;++q){
    const float4 a = ((const float4*)(predb+2*NPIX))[v+q];
    so[4*q]=a.x; so[4*q+1]=a.y; so[4*q+2]=a.z; so[4*q+3]=a.w;
  }
  #pragma unroll
  for (int q=0;q<4;++q){
    const float4 a = ((const float4*)(predb+5*NPIX))[v+q];
    sp[4*q]=a.x; sp[4*q+1]=a.y; sp[4*q+2]=a.z; sp[4*q+3]=a.w;
  }
  float c0=0,c1=0,c2=0,c3=0,c4=0; int cur=-1;
#define FLUSH_ACC() if (cur>=0){ float* a=&acc[cur*5]; atomicAdd(a,c0); atomicAdd(a+1,c1); \
    atomicAdd(a+2,c2); atomicAdd(a+3,c3); atomicAdd(a+4,c4); }
  #pragma unroll
  for (int j=0;j<16;++j){
    const int id = oid[j];
    if (id>=1 && id<=NOBJ){
      const int slot = id-1;
      if (slot != cur){ FLUSH_ACC(); cur=slot; c0=c1=c2=c3=c4=0.f; }
      const int pix = pix0+j;
      c0 += 1.f; c1 += (float)(pix & 511)*INV511; c2 += (float)(pix >> 9)*INV511;
      const float s=so[j]; c3 += s; c4 += s*s;
    }
  }
  FLUSH_ACC();
  c0=c1=c2=c3=c4=0.f; cur=-1;
  #pragma unroll
  for (int j=0;j<16;++j){
    const int id = pid[j];
    if (id>=1 && id<=NPART){
      const int slot = NOBJ + id-1;
      if (slot != cur){ FLUSH_ACC(); cur=slot; c0=c1=c2=c3=c4=0.f; }
      const int pix = pix0+j;
      c0 += 1.f; c1 += (float)(pix & 511)*INV511; c2 += (float)(pix >> 9)*INV511;
      const float s=sp[j]; c3 += s; c4 += s*s;
    }
  }
  FLUSH_ACC();
#undef FLUSH_ACC
  __syncthreads();
  if (tid < NINST*5 && acc[tid] != 0.f) atomicAdd(&accum[img*NINST*5 + tid], acc[tid]);
}

// Fused single-pass: grid (Cn, B), 256 thr, 4 px/thread/iter, all 24 instances.
// Inlines params (from accum), var term (chunk==0), both seed losses.
__global__ __launch_bounds__(256) void k_main(
    const float* __restrict__ pred, const int* __restrict__ obj_inst,
    const int* __restrict__ parts_inst, const float* __restrict__ accum,
    unsigned* __restrict__ part, float* __restrict__ out, int Cn){
  __shared__ unsigned h[NINST*KB];       // 12KB
  __shared__ float pz[NINST*3];          // cx, cy, aa
  __shared__ float ssl;
  const int tid = threadIdx.x;
  for (int i = tid; i < NINST*KB; i += 256) h[i] = 0u;
  if (tid == 0) ssl = 0.f;
  const int chunk = blockIdx.x, img = blockIdx.y;
  if (tid < NINST){
    const float* a = accum + (img*NINST + tid)*5;
    const float cnt = a[0];
    float cx=0.f, cy=0.f, aa=-0.72134752f, var=0.f;
    if (cnt > 0.5f){
      const float inv = 1.0f/cnt;
      cx = a[1]*inv; cy = a[2]*inv;
      const float s = a[3]*inv;
      var = a[4]*inv - s*s; if (var < 0.f) var = 0.f;
      aa = -0.72134752f*expf(5.5f*s);    // -0.5*log2(e)*l11
    }
    pz[tid*3]=cx; pz[tid*3+1]=cy; pz[tid*3+2]=aa;
    if (chunk == 0 && cnt > 0.5f){
      const float wN = (tid < NOBJ) ? 8.f : 16.f;
      atomicAdd(out, var * (10.0f/(wN*BATCH)));
    }
  }
  __syncthreads();
  float cx[NINST], cy[NINST], aa[NINST];
  #pragma unroll
  for (int i=0;i<NINST;++i){ cx[i]=pz[i*3]; cy[i]=pz[i*3+1]; aa[i]=pz[i*3+2]; }
  const float* predb = pred + (size_t)img*8*NPIX;
  const int* omap = obj_inst   + (size_t)img*NPIX;
  const int* pmap = parts_inst + (size_t)img*NPIX;
  float sl = 0.f;
  const int chunkpix = NPIX / Cn;
  const int base = chunk * chunkpix;
  const int iters = chunkpix >> 10;      // 256 thr * 4 px
  for (int it=0; it<iters; ++it){
    const int pix0 = base + (it<<10) + tid*4;
    const int v = pix0 >> 2;
    const float4 t0 = ((const float4*)(predb + 0*NPIX))[v];
    const float4 t1 = ((const float4*)(predb + 1*NPIX))[v];
    const float4 t3 = ((const float4*)(predb + 3*NPIX))[v];
    const float4 t4 = ((const float4*)(predb + 4*NPIX))[v];
    const float4 s6 = ((const float4*)(predb + 6*NPIX))[v];
    const float4 s7 = ((const float4*)(predb + 7*NPIX))[v];
    const int4   om4 = ((const int4*)omap)[v];
    const int4   pm4 = ((const int4*)pmap)[v];
    const float a0[4] = {t0.x,t0.y,t0.z,t0.w};
    const float a1[4] = {t1.x,t1.y,t1.z,t1.w};
    const float a3[4] = {t3.x,t3.y,t3.z,t3.w};
    const float a4[4] = {t4.x,t4.y,t4.z,t4.w};
    const float d6[4] = {s6.x,s6.y,s6.z,s6.w};
    const float d7[4] = {s7.x,s7.y,s7.z,s7.w};
    const int   om[4] = {om4.x,om4.y,om4.z,om4.w};
    const int   pm[4] = {pm4.x,pm4.y,pm4.z,pm4.w};
    #pragma unroll
    for (int j=0;j<4;++j){
      const int pix = pix0 + j;
      const float xm = (float)(pix & 511)*INV511;
      const float ym = (float)(pix >> 9)*INV511;
      const float ep0 = xm + ftanh(a3[j]);       // parts emb
      const float ep1 = ym + ftanh(a4[j]);
      const float eo0 = ep0 + ftanh(a0[j]);      // obj emb
      const float eo1 = ep1 + ftanh(a1[j]);
      const int lio = om[j] - 1;                 // 0..7 when obj fg
      const int lip = pm[j] - 1;                 // 0..15 when parts fg
      const float so = fsig(d6[j]);
      const float sp = fsig(d7[j]);
      float pwo = 0.f, pwp = 0.f;
      #pragma unroll
      for (int i=0;i<NOBJ;++i){
        const float dx = eo0-cx[i], dy = eo1-cy[i];
        const float p = fexp2(aa[i]*(dx*dx + dy*dy));
        int ib = (int)(p * (float)KB); if (ib > KB-1) ib = KB-1;
        const bool lab = (lio == i);
        if (lab) pwo = p;
        atomicAdd(&h[i*KB + (lab ? (KB-1-ib) : ib)], lab ? 0x10001u : 1u);
      }
      #pragma unroll
      for (int i=0;i<NPART;++i){
        const int ii = NOBJ + i;
        const float dx = ep0-cx[ii], dy = ep1-cy[ii];
        const float p = fexp2(aa[ii]*(dx*dx + dy*dy));
        int ib = (int)(p * (float)KB); if (ib > KB-1) ib = KB-1;
        const bool lab = (lip == i);
        if (lab) pwp = p;
        atomicAdd(&h[ii*KB + (lab ? (KB-1-ib) : ib)], lab ? 0x10001u : 1u);
      }
      const float dso = (lio >= 0) ? (so - pwo) : so;   // bg: label!=1 <=> inst==0
      const float dsp = (lip >= 0) ? (sp - pwp) : sp;
      sl += dso*dso + dsp*dsp;
    }
  }
  for (int off=32; off>0; off>>=1) sl += __shfl_down(sl, off);
  if ((tid & 63)==0) atomicAdd(&ssl, sl);
  __syncthreads();
  unsigned* dst = part + ((size_t)img*NINST*Cn + chunk)*KB;
  for (int i = tid; i < NINST*KB; i += 256){
    const int hi = i >> 7;               // KB == 128
    const int bin = i & (KB-1);
    dst[(size_t)hi*Cn*KB + bin] = h[i];
  }
  if (tid == 0) atomicAdd(out, ssl * (1.0f/((float)NPIX*BATCH)));
}

// grid (B*NINST), KB thr: thread t owns bin t; coalesced Cn-sum (unrolled), block scan, loss.
__global__ __launch_bounds__(KB) void k_lovasz(
    const unsigned* __restrict__ part, const float* __restrict__ accum,
    float* __restrict__ out, int Cn){
  __shared__ float sc[KB], sg[KB];
  __shared__ float wt[16];
  __shared__ float lsum[8];
  const int blk = blockIdx.x;            // == img*NINST + inst
  const int inst = blk % NINST;
  const float gts = accum[blk*5];
  if (gts < 0.5f) return;                // block-uniform exit
  const int t = threadIdx.x;
  const unsigned* pb = part + (size_t)blk*Cn*KB;
  unsigned cnt=0u, fg=0u;
  #pragma unroll 16
  for (int c=0;c<Cn;++c){ const unsigned w = pb[(size_t)c*KB + t]; cnt += w & 0xFFFFu; fg += w >> 16; }
  sc[KB-1-t] = (float)cnt; sg[KB-1-t] = (float)fg;   // descending-error order
  __syncthreads();
  const float c = sc[t], g = sg[t];
  float ic = c, ig = g;
  for (int off=1; off<64; off<<=1){
    const float tc = __shfl_up(ic, off); const float tg = __shfl_up(ig, off);
    if ((t & 63) >= off){ ic += tc; ig += tg; }
  }
  const int wid = t >> 6, lane = t & 63;
  if (lane == 63){ wt[wid] = ic; wt[8+wid] = ig; }
  __syncthreads();
  float offc = 0.f, offg = 0.f;
  for (int w2=0; w2<wid; ++w2){ offc += wt[w2]; offg += wt[8+w2]; }
  const float C1 = offc + ic, G1 = offg + ig, C0 = C1 - c, G0 = G1 - g;
  float l = 0.f;
  if (c > 0.f){
    const int bin = KB-1-t;
    const float e = (bin + 0.5f)*(2.0f/KB);
    const float jb = 1.f - (gts-G0)/(gts + C0 - G0);
    const float ja = 1.f - (gts-G1)/(gts + C1 - G1);
    l = e*(ja - jb);
  }
  for (int off=32; off>0; off>>=1) l += __shfl_down(l, off);
  if (lane == 0) lsum[wid] = l;
  __syncthreads();
  if (t == 0){
    float tot = 0.f;
    #pragma unroll
    for (int w2=0; w2<(KB/64); ++w2) tot += lsum[w2];
    const float wN = (inst < NOBJ) ? 8.f : 16.f;
    atomicAdd(out, tot * (1.0f/(wN*BATCH)));
  }
}

extern "C" void kernel_launch(void* const* d_in, const int* in_sizes, int n_in,
                              void* d_out, int out_size, void* d_ws, size_t ws_size,
                              hipStream_t stream){
  (void)in_sizes; (void)n_in; (void)out_size;
  const float* pred       = (const float*)d_in[0];
  const int*   obj_inst   = (const int*)d_in[1];
  const int*   parts_inst = (const int*)d_in[3];
  float* out = (float*)d_out;

  const size_t need256 = (size_t)BATCH*NINST*256*KB*4 + 8192;
  const int Cn = (ws_size >= need256) ? 256 : 128;
  unsigned* part = (unsigned*)d_ws;
  const size_t partWords = (size_t)BATCH*NINST*Cn*KB;
  float* accum  = (float*)((unsigned*)d_ws + partWords);

  hipMemsetAsync(out, 0, sizeof(float), stream);
  hipMemsetAsync(accum, 0, BATCH*NINST*5*sizeof(float), stream);
  hipLaunchKernelGGL(k_reduce, dim3(NPIX/4096, BATCH), dim3(256), 0, stream,
                     pred, obj_inst, parts_inst, accum);
  hipLaunchKernelGGL(k_main, dim3(Cn, BATCH), dim3(256), 0, stream,
                     pred, obj_inst, parts_inst, accum, part, out, Cn);
  hipLaunchKernelGGL(k_lovasz, dim3(BATCH*NINST), dim3(KB), 0, stream, part, accum, out, Cn);
}

// Round 16
// 123.460 us; speedup vs baseline: 1.0413x; 1.0413x over previous
//
#include <hip/hip_runtime.h>

#define BATCH 4
#define NPIX (512*512)
#define NOBJ 8
#define NPART 16
#define NINST 24
#define KB 256
#define L2E 1.44269504f
#define INV511 (1.0f/511.0f)

__device__ __forceinline__ float fexp2(float x){ return __builtin_amdgcn_exp2f(x); }
__device__ __forceinline__ float frcp(float x){ return __builtin_amdgcn_rcpf(x); }
__device__ __forceinline__ float ftanh(float x){ return 1.f - 2.f*frcp(fexp2(2.f*L2E*x) + 1.f); }
__device__ __forceinline__ float fsig(float x){ return frcp(1.f + fexp2(-L2E*x)); }

// ws: [0, B*24*Cn*KB) u32 partial hists packed (cnt | fg<<16), layout [instG][Cn][KB]
//     then accum f32 [B][24][5] (cnt, sx, sy, ssig, ssig2)

__global__ void k_zero(float* __restrict__ acc, float* __restrict__ out){
  const int i = threadIdx.x;
  if (i < BATCH*NINST*5) acc[i] = 0.f;
  if (i == 0) out[0] = 0.f;
}

// grid (NPIX/4096, BATCH), 256 thr, 16 px/thread vec4 (run-combined LDS atomics).
__global__ __launch_bounds__(256) void k_reduce(
    const float* __restrict__ pred, const int* __restrict__ obj_inst,
    const int* __restrict__ parts_inst, float* __restrict__ accum){
  __shared__ float acc[NINST*5];
  const int tid = threadIdx.x;
  if (tid < NINST*5) acc[tid] = 0.f;
  __syncthreads();
  const int img = blockIdx.y;
  const float* predb = pred + (size_t)img*8*NPIX;
  const int pix0 = blockIdx.x*4096 + tid*16;
  const int v = pix0 >> 2;
  const int*   obase = obj_inst   + (size_t)img*NPIX;
  const int*   pbase = parts_inst + (size_t)img*NPIX;
  int   oid[16], pid[16];
  float so[16], sp[16];
  #pragma unroll
  for (int q=0;q<4;++q){
    const int4 a = ((const int4*)obase)[v+q];
    oid[4*q]=a.x; oid[4*q+1]=a.y; oid[4*q+2]=a.z; oid[4*q+3]=a.w;
  }
  #pragma unroll
  for (int q=0;q<4;++q){
    const int4 a = ((const int4*)pbase)[v+q];
    pid[4*q]=a.x; pid[4*q+1]=a.y; pid[4*q+2]=a.z; pid[4*q+3]=a.w;
  }
  #pragma unroll
  for (int q=0;q<4;++q){
    const float4 a = ((const float4*)(predb+2*NPIX))[v+q];
    so[4*q]=a.x; so[4*q+1]=a.y; so[4*q+2]=a.z; so[4*q+3]=a.w;
  }
  #pragma unroll
  for (int q=0;q<4;++q){
    const float4 a = ((const float4*)(predb+5*NPIX))[v+q];
    sp[4*q]=a.x; sp[4*q+1]=a.y; sp[4*q+2]=a.z; sp[4*q+3]=a.w;
  }
  float c0=0,c1=0,c2=0,c3=0,c4=0; int cur=-1;
#define FLUSH_ACC() if (cur>=0){ float* a=&acc[cur*5]; atomicAdd(a,c0); atomicAdd(a+1,c1); \
    atomicAdd(a+2,c2); atomicAdd(a+3,c3); atomicAdd(a+4,c4); }
  #pragma unroll
  for (int j=0;j<16;++j){
    const int id = oid[j];
    if (id>=1 && id<=NOBJ){
      const int slot = id-1;
      if (slot != cur){ FLUSH_ACC(); cur=slot; c0=c1=c2=c3=c4=0.f; }
      const int pix = pix0+j;
      c0 += 1.f; c1 += (float)(pix & 511)*INV511; c2 += (float)(pix >> 9)*INV511;
      const float s=so[j]; c3 += s; c4 += s*s;
    }
  }
  FLUSH_ACC();
  c0=c1=c2=c3=c4=0.f; cur=-1;
  #pragma unroll
  for (int j=0;j<16;++j){
    const int id = pid[j];
    if (id>=1 && id<=NPART){
      const int slot = NOBJ + id-1;
      if (slot != cur){ FLUSH_ACC(); cur=slot; c0=c1=c2=c3=c4=0.f; }
      const int pix = pix0+j;
      c0 += 1.f; c1 += (float)(pix & 511)*INV511; c2 += (float)(pix >> 9)*INV511;
      const float s=sp[j]; c3 += s; c4 += s*s;
    }
  }
  FLUSH_ACC();
#undef FLUSH_ACC
  __syncthreads();
  if (tid < NINST*5 && acc[tid] != 0.f) atomicAdd(&accum[img*NINST*5 + tid], acc[tid]);
}

// Fused single-pass: grid (Cn, B), 256 thr, 4 px/thread/iter, all 24 instances.
// Inlines params (from accum), var term (chunk==0), both seed losses.
__global__ __launch_bounds__(256) void k_main(
    const float* __restrict__ pred, const int* __restrict__ obj_inst,
    const int* __restrict__ parts_inst, const float* __restrict__ accum,
    unsigned* __restrict__ part, float* __restrict__ out, int Cn){
  __shared__ unsigned h[NINST*KB];       // 24KB
  __shared__ float pz[NINST*3];          // cx, cy, aa
  __shared__ float ssl;
  const int tid = threadIdx.x;
  for (int i = tid; i < NINST*KB; i += 256) h[i] = 0u;
  if (tid == 0) ssl = 0.f;
  const int chunk = blockIdx.x, img = blockIdx.y;
  if (tid < NINST){
    const float* a = accum + (img*NINST + tid)*5;
    const float cnt = a[0];
    float cx=0.f, cy=0.f, aa=-0.72134752f, var=0.f;
    if (cnt > 0.5f){
      const float inv = 1.0f/cnt;
      cx = a[1]*inv; cy = a[2]*inv;
      const float s = a[3]*inv;
      var = a[4]*inv - s*s; if (var < 0.f) var = 0.f;
      aa = -0.72134752f*expf(5.5f*s);    // -0.5*log2(e)*l11
    }
    pz[tid*3]=cx; pz[tid*3+1]=cy; pz[tid*3+2]=aa;
    if (chunk == 0 && cnt > 0.5f){
      const float wN = (tid < NOBJ) ? 8.f : 16.f;
      atomicAdd(out, var * (10.0f/(wN*BATCH)));
    }
  }
  __syncthreads();
  float cx[NINST], cy[NINST], aa[NINST];
  #pragma unroll
  for (int i=0;i<NINST;++i){ cx[i]=pz[i*3]; cy[i]=pz[i*3+1]; aa[i]=pz[i*3+2]; }
  const float* predb = pred + (size_t)img*8*NPIX;
  const int* omap = obj_inst   + (size_t)img*NPIX;
  const int* pmap = parts_inst + (size_t)img*NPIX;
  float sl = 0.f;
  const int chunkpix = NPIX / Cn;
  const int base = chunk * chunkpix;
  const int iters = chunkpix >> 10;      // 256 thr * 4 px
  for (int it=0; it<iters; ++it){
    const int pix0 = base + (it<<10) + tid*4;
    const int v = pix0 >> 2;
    const float4 t0 = ((const float4*)(predb + 0*NPIX))[v];
    const float4 t1 = ((const float4*)(predb + 1*NPIX))[v];
    const float4 t3 = ((const float4*)(predb + 3*NPIX))[v];
    const float4 t4 = ((const float4*)(predb + 4*NPIX))[v];
    const float4 s6 = ((const float4*)(predb + 6*NPIX))[v];
    const float4 s7 = ((const float4*)(predb + 7*NPIX))[v];
    const int4   om4 = ((const int4*)omap)[v];
    const int4   pm4 = ((const int4*)pmap)[v];
    const float a0[4] = {t0.x,t0.y,t0.z,t0.w};
    const float a1[4] = {t1.x,t1.y,t1.z,t1.w};
    const float a3[4] = {t3.x,t3.y,t3.z,t3.w};
    const float a4[4] = {t4.x,t4.y,t4.z,t4.w};
    const float d6[4] = {s6.x,s6.y,s6.z,s6.w};
    const float d7[4] = {s7.x,s7.y,s7.z,s7.w};
    const int   om[4] = {om4.x,om4.y,om4.z,om4.w};
    const int   pm[4] = {pm4.x,pm4.y,pm4.z,pm4.w};
    #pragma unroll
    for (int j=0;j<4;++j){
      const int pix = pix0 + j;
      const float xm = (float)(pix & 511)*INV511;
      const float ym = (float)(pix >> 9)*INV511;
      const float ep0 = xm + ftanh(a3[j]);       // parts emb
      const float ep1 = ym + ftanh(a4[j]);
      const float eo0 = ep0 + ftanh(a0[j]);      // obj emb
      const float eo1 = ep1 + ftanh(a1[j]);
      const int lio = om[j] - 1;                 // 0..7 when obj fg
      const int lip = pm[j] - 1;                 // 0..15 when parts fg
      const float so = fsig(d6[j]);
      const float sp = fsig(d7[j]);
      float pwo = 0.f, pwp = 0.f;
      #pragma unroll
      for (int i=0;i<NOBJ;++i){
        const float dx = eo0-cx[i], dy = eo1-cy[i];
        const float p = fexp2(aa[i]*(dx*dx + dy*dy));
        int ib = (int)(p * (float)KB); if (ib > KB-1) ib = KB-1;
        const bool lab = (lio == i);
        if (lab) pwo = p;
        atomicAdd(&h[i*KB + (lab ? (KB-1-ib) : ib)], lab ? 0x10001u : 1u);
      }
      #pragma unroll
      for (int i=0;i<NPART;++i){
        const int ii = NOBJ + i;
        const float dx = ep0-cx[ii], dy = ep1-cy[ii];
        const float p = fexp2(aa[ii]*(dx*dx + dy*dy));
        int ib = (int)(p * (float)KB); if (ib > KB-1) ib = KB-1;
        const bool lab = (lip == i);
        if (lab) pwp = p;
        atomicAdd(&h[ii*KB + (lab ? (KB-1-ib) : ib)], lab ? 0x10001u : 1u);
      }
      const float dso = (lio >= 0) ? (so - pwo) : so;   // bg: label!=1 <=> inst==0
      const float dsp = (lip >= 0) ? (sp - pwp) : sp;
      sl += dso*dso + dsp*dsp;
    }
  }
  for (int off=32; off>0; off>>=1) sl += __shfl_down(sl, off);
  if ((tid & 63)==0) atomicAdd(&ssl, sl);
  __syncthreads();
  unsigned* dst = part + ((size_t)img*NINST*Cn + chunk)*KB;
  for (int i = tid; i < NINST*KB; i += 256){
    const int hi = i >> 8;
    const int bin = i & (KB-1);
    dst[(size_t)hi*Cn*KB + bin] = h[i];
  }
  if (tid == 0) atomicAdd(out, ssl * (1.0f/((float)NPIX*BATCH)));
}

// grid (B*NINST), KB thr: thread t owns bin t; coalesced Cn-sum (unrolled), block scan, loss.
__global__ __launch_bounds__(KB) void k_lovasz(
    const unsigned* __restrict__ part, const float* __restrict__ accum,
    float* __restrict__ out, int Cn){
  __shared__ float sc[KB], sg[KB];
  __shared__ float wt[16];
  __shared__ float lsum[8];
  const int blk = blockIdx.x;            // == img*NINST + inst
  const int inst = blk % NINST;
  const float gts = accum[blk*5];
  if (gts < 0.5f) return;                // block-uniform exit
  const int t = threadIdx.x;
  const unsigned* pb = part + (size_t)blk*Cn*KB;
  unsigned cnt=0u, fg=0u;
  #pragma unroll 16
  for (int c=0;c<Cn;++c){ const unsigned w = pb[(size_t)c*KB + t]; cnt += w & 0xFFFFu; fg += w >> 16; }
  sc[KB-1-t] = (float)cnt; sg[KB-1-t] = (float)fg;   // descending-error order
  __syncthreads();
  const float c = sc[t], g = sg[t];
  float ic = c, ig = g;
  for (int off=1; off<64; off<<=1){
    const float tc = __shfl_up(ic, off); const float tg = __shfl_up(ig, off);
    if ((t & 63) >= off){ ic += tc; ig += tg; }
  }
  const int wid = t >> 6, lane = t & 63;
  if (lane == 63){ wt[wid] = ic; wt[8+wid] = ig; }
  __syncthreads();
  float offc = 0.f, offg = 0.f;
  for (int w2=0; w2<wid; ++w2){ offc += wt[w2]; offg += wt[8+w2]; }
  const float C1 = offc + ic, G1 = offg + ig, C0 = C1 - c, G0 = G1 - g;
  float l = 0.f;
  if (c > 0.f){
    const int bin = KB-1-t;
    const float e = (bin + 0.5f)*(2.0f/KB);
    const float jb = 1.f - (gts-G0)/(gts + C0 - G0);
    const float ja = 1.f - (gts-G1)/(gts + C1 - G1);
    l = e*(ja - jb);
  }
  for (int off=32; off>0; off>>=1) l += __shfl_down(l, off);
  if (lane == 0) lsum[wid] = l;
  __syncthreads();
  if (t == 0){
    float tot = 0.f;
    #pragma unroll
    for (int w2=0; w2<(KB/64); ++w2) tot += lsum[w2];
    const float wN = (inst < NOBJ) ? 8.f : 16.f;
    atomicAdd(out, tot * (1.0f/(wN*BATCH)));
  }
}

extern "C" void kernel_launch(void* const* d_in, const int* in_sizes, int n_in,
                              void* d_out, int out_size, void* d_ws, size_t ws_size,
                              hipStream_t stream){
  (void)in_sizes; (void)n_in; (void)out_size;
  const float* pred       = (const float*)d_in[0];
  const int*   obj_inst   = (const int*)d_in[1];
  const int*   parts_inst = (const int*)d_in[3];
  float* out = (float*)d_out;

  const size_t need128 = (size_t)BATCH*NINST*128*KB*4 + 8192;
  const int Cn = (ws_size >= need128) ? 128 : 64;
  unsigned* part = (unsigned*)d_ws;
  const size_t partWords = (size_t)BATCH*NINST*Cn*KB;
  float* accum  = (float*)((unsigned*)d_ws + partWords);

  hipLaunchKernelGGL(k_zero, dim3(1), dim3(512), 0, stream, accum, out);
  hipLaunchKernelGGL(k_reduce, dim3(NPIX/4096, BATCH), dim3(256), 0, stream,
                     pred, obj_inst, parts_inst, accum);
  hipLaunchKernelGGL(k_main, dim3(Cn, BATCH), dim3(256), 0, stream,
                     pred, obj_inst, parts_inst, accum, part, out, Cn);
  hipLaunchKernelGGL(k_lovasz, dim3(BATCH*NINST), dim3(KB), 0, stream, part, accum, out, Cn);
}